// Round 1
// baseline (8818.349 us; speedup 1.0000x reference)
//
#include <hip/hip_runtime.h>
#include <math.h>

#define HWD 1089
#define WD 33
#define NF 128
#define NJ 124
#define CC 32

__device__ __forceinline__ float sigm(float z) { return 1.f / (1.f + expf(-z)); }

// ---------------- rs[j] = sum_k mlp_w[j][k] ----------------
__global__ void rowsum_k(const float* __restrict__ mw, float* __restrict__ rs) {
    int j = blockIdx.x;
    const float* row = mw + (size_t)j * HWD;
    float s = 0.f;
    for (int k = threadIdx.x; k < HWD; k += 256) s += row[k];
    __shared__ float red[256];
    red[threadIdx.x] = s; __syncthreads();
    for (int off = 128; off > 0; off >>= 1) {
        if (threadIdx.x < off) red[threadIdx.x] += red[threadIdx.x + off];
        __syncthreads();
    }
    if (threadIdx.x == 0) rs[j] = red[0];
}

// ---------------- imgs = x * sigmoid((t/20)*rs + mlp_b) ----------------
__global__ void imgs_k(const float* __restrict__ x, const float* __restrict__ rs,
                       const float* __restrict__ mb, float* __restrict__ imgs) {
    int idx = blockIdx.x * 256 + threadIdx.x;
    if (idx >= NF * HWD) return;
    int t = idx / HWD, p = idx % HWD;
    float pe = sigm(((float)t / 20.0f) * rs[p] + mb[p]);
    imgs[idx] = x[idx] * pe;
}

// ---------------- generic 3x3 conv, pad=1 ----------------
template <int CIN, int COUT, bool RELU, bool HAS_B, bool HAS_RES>
__global__ void conv3x3_k(const float* __restrict__ in, int in_ns,
                          const float* __restrict__ w, const float* __restrict__ b,
                          const float* __restrict__ res, int res_ns,
                          float* __restrict__ out, int out_ns, int N) {
    __shared__ float wl[COUT * CIN * 9];
    for (int i = threadIdx.x; i < COUT * CIN * 9; i += blockDim.x) wl[i] = w[i];
    __syncthreads();
    int idx = blockIdx.x * blockDim.x + threadIdx.x;
    if (idx >= N * HWD) return;
    int n = idx / HWD, p = idx % HWD;
    int h = p / WD, q = p % WD;
    float acc[COUT];
#pragma unroll
    for (int o = 0; o < COUT; ++o) acc[o] = HAS_B ? b[o] : 0.f;
    const float* inn = in + (size_t)n * in_ns;
    for (int c = 0; c < CIN; ++c) {
        float v[9];
#pragma unroll
        for (int k = 0; k < 9; ++k) {
            int hh = h + k / 3 - 1, qq = q + k % 3 - 1;
            v[k] = (hh >= 0 && hh < WD && qq >= 0 && qq < WD) ? inn[c * HWD + hh * WD + qq] : 0.f;
        }
#pragma unroll
        for (int o = 0; o < COUT; ++o) {
            const float* wp = &wl[(o * CIN + c) * 9];
            float s = v[0]*wp[0] + v[1]*wp[1] + v[2]*wp[2]
                    + v[3]*wp[3] + v[4]*wp[4] + v[5]*wp[5]
                    + v[6]*wp[6] + v[7]*wp[7] + v[8]*wp[8];
            acc[o] += s;
        }
    }
#pragma unroll
    for (int o = 0; o < COUT; ++o) {
        float val = acc[o];
        if (RELU) val = fmaxf(val, 0.f);
        if (HAS_RES) val += res[(size_t)n * res_ns + o * HWD + p];
        out[(size_t)n * out_ns + o * HWD + p] = val;
    }
}

// ---------------- a1c = 1x1 conv (16 out) of feats[n+2] ----------------
__global__ void a1c_k(const float* __restrict__ feats, const float* __restrict__ w,
                      const float* __restrict__ b, float* __restrict__ a1c) {
    int idx = blockIdx.x * 256 + threadIdx.x;
    if (idx >= NJ * HWD) return;
    int n = idx / HWD, p = idx % HWD;
    const float* f = feats + (size_t)(n + 2) * CC * HWD + p;
    float fv[CC];
#pragma unroll
    for (int c = 0; c < CC; ++c) fv[c] = f[c * HWD];
#pragma unroll
    for (int o = 0; o < 16; ++o) {
        float acc = b[o];
#pragma unroll
        for (int c = 0; c < CC; ++c) acc += w[o * CC + c] * fv[c];
        a1c[((size_t)n * 16 + o) * HWD + p] = acc;
    }
}

// ---------------- a2 = 1x1 conv of neig; agg = [mean, max] over concat(a1c,a2) ----------------
__global__ void a2agg_k(const float* __restrict__ feats, const float* __restrict__ w,
                        const float* __restrict__ b, const float* __restrict__ a1c,
                        float* __restrict__ a2, float* __restrict__ agg, int xoff) {
    int idx = blockIdx.x * 256 + threadIdx.x;
    if (idx >= NJ * HWD) return;
    int n = idx / HWD, p = idx % HWD;
    const float* f = feats + (size_t)(n + xoff) * CC * HWD + p;
    float fv[CC];
#pragma unroll
    for (int c = 0; c < CC; ++c) fv[c] = f[c * HWD];
    float sum = 0.f, mx = -1e30f;
#pragma unroll
    for (int o = 0; o < 16; ++o) {
        float v = a1c[((size_t)n * 16 + o) * HWD + p];
        sum += v; mx = fmaxf(mx, v);
    }
#pragma unroll
    for (int o = 0; o < 16; ++o) {
        float acc = b[o];
#pragma unroll
        for (int c = 0; c < CC; ++c) acc += w[o * CC + c] * fv[c];
        a2[((size_t)n * 16 + o) * HWD + p] = acc;
        sum += acc; mx = fmaxf(mx, acc);
    }
    agg[((size_t)n * 2 + 0) * HWD + p] = sum * (1.f / 32.f);
    agg[((size_t)n * 2 + 1) * HWD + p] = mx;
}

// ---------------- sig = sigmoid(conv3x3(agg, sq_w, sq_b)); fused = [a1c*sig0, a2*sig1] ----------------
__global__ void sigfused_k(const float* __restrict__ agg, const float* __restrict__ sqw,
                           const float* __restrict__ sqb, const float* __restrict__ a1c,
                           const float* __restrict__ a2, float* __restrict__ fused) {
    int idx = blockIdx.x * 256 + threadIdx.x;
    if (idx >= NJ * HWD) return;
    int n = idx / HWD, p = idx % HWD;
    int h = p / WD, q = p % WD;
    float s0 = sqb[0], s1 = sqb[1];
    const float* ag = agg + (size_t)n * 2 * HWD;
#pragma unroll
    for (int c = 0; c < 2; ++c) {
#pragma unroll
        for (int k = 0; k < 9; ++k) {
            int hh = h + k / 3 - 1, qq = q + k % 3 - 1;
            if (hh >= 0 && hh < WD && qq >= 0 && qq < WD) {
                float v = ag[c * HWD + hh * WD + qq];
                s0 += v * sqw[(0 * 2 + c) * 9 + k];
                s1 += v * sqw[(1 * 2 + c) * 9 + k];
            }
        }
    }
    float g0 = sigm(s0), g1 = sigm(s1);
#pragma unroll
    for (int o = 0; o < 16; ++o)
        fused[((size_t)n * CC + o) * HWD + p] = a1c[((size_t)n * 16 + o) * HWD + p] * g0;
#pragma unroll
    for (int o = 0; o < 16; ++o)
        fused[((size_t)n * CC + 16 + o) * HWD + p] = a2[((size_t)n * 16 + o) * HWD + p] * g1;
}

// ---------------- deformable conv 3x3, 32->32 ----------------
__global__ void deform_k(const float* __restrict__ xbase, int xoff,
                         const float* __restrict__ off, const float* __restrict__ w,
                         float* __restrict__ out) {
    __shared__ float wl[CC * CC * 9];
    for (int i = threadIdx.x; i < CC * CC * 9; i += blockDim.x) wl[i] = w[i];
    __syncthreads();
    int idx = blockIdx.x * blockDim.x + threadIdx.x;
    if (idx >= NJ * HWD) return;
    int n = idx / HWD, p = idx % HWD;
    int h = p / WD, q = p % WD;
    const float* xf = xbase + (size_t)(n + xoff) * CC * HWD;
    const float* ofn = off + (size_t)n * 18 * HWD + p;
    float acc[CC];
#pragma unroll
    for (int o = 0; o < CC; ++o) acc[o] = 0.f;
    for (int kk = 0; kk < 9; ++kk) {
        float dy = ofn[(2 * kk) * HWD];
        float dx = ofn[(2 * kk + 1) * HWD];
        float py = (float)(h - 1 + kk / 3) + dy;
        float px = (float)(q - 1 + kk % 3) + dx;
        float y0f = floorf(py), x0f = floorf(px);
        float ly = py - y0f, lx = px - x0f;
        int y0 = (int)y0f, x0 = (int)x0f;
        float w00 = (1.f - ly) * (1.f - lx), w01 = (1.f - ly) * lx;
        float w10 = ly * (1.f - lx), w11 = ly * lx;
        bool yv0 = (y0 >= 0 && y0 < WD), yv1 = (y0 + 1 >= 0 && y0 + 1 < WD);
        bool xv0 = (x0 >= 0 && x0 < WD), xv1 = (x0 + 1 >= 0 && x0 + 1 < WD);
        if (!(yv0 && xv0)) w00 = 0.f;
        if (!(yv0 && xv1)) w01 = 0.f;
        if (!(yv1 && xv0)) w10 = 0.f;
        if (!(yv1 && xv1)) w11 = 0.f;
        int yc0 = min(max(y0, 0), WD - 1), yc1 = min(max(y0 + 1, 0), WD - 1);
        int xc0 = min(max(x0, 0), WD - 1), xc1 = min(max(x0 + 1, 0), WD - 1);
        int i00 = yc0 * WD + xc0, i01 = yc0 * WD + xc1;
        int i10 = yc1 * WD + xc0, i11 = yc1 * WD + xc1;
        for (int c = 0; c < CC; ++c) {
            const float* xc = xf + c * HWD;
            float s = xc[i00] * w00 + xc[i01] * w01 + xc[i10] * w10 + xc[i11] * w11;
#pragma unroll
            for (int o = 0; o < CC; ++o) acc[o] += s * wl[(o * CC + c) * 9 + kk];
        }
    }
#pragma unroll
    for (int o = 0; o < CC; ++o) out[((size_t)n * CC + o) * HWD + p] = acc[o];
}

// ---------------- cen_raw into aligned ch2 + arange output ----------------
__global__ void misc_k(const float* __restrict__ imgs, float* __restrict__ out) {
    int idx = blockIdx.x * 256 + threadIdx.x;
    float* alig = out + 135036 + 124;
    if (idx < NJ * HWD) {
        int n = idx / HWD, p = idx % HWD;
        alig[((size_t)n * 5 + 2) * HWD + p] = imgs[(size_t)(n + 2) * HWD + p];
    }
    if (idx < NJ) out[135036 + idx] = (float)(idx + 2);
}

extern "C" void kernel_launch(void* const* d_in, const int* in_sizes, int n_in,
                              void* d_out, int out_size, void* d_ws, size_t ws_size,
                              hipStream_t stream) {
    const float* x      = (const float*)d_in[0];
    const float* mlp_w  = (const float*)d_in[1];
    const float* mlp_b  = (const float*)d_in[2];
    const float* fe_w   = (const float*)d_in[3];
    const float* fe_b   = (const float*)d_in[4];
    const float* c0_w   = (const float*)d_in[5];
    const float* c0_b   = (const float*)d_in[6];
    const float* c1_w   = (const float*)d_in[7];
    const float* c1_b   = (const float*)d_in[8];
    const float* sq_w   = (const float*)d_in[9];
    const float* sq_b   = (const float*)d_in[10];
    const float* off1_w = (const float*)d_in[11];
    const float* off1_b = (const float*)d_in[12];
    const float* dw1    = (const float*)d_in[13];
    const float* off2_w = (const float*)d_in[14];
    const float* off2_b = (const float*)d_in[15];
    const float* dw2    = (const float*)d_in[16];
    const float* conv_w = (const float*)d_in[17];
    const float* conv_b = (const float*)d_in[18];
    const float* tc0_w  = (const float*)d_in[19];
    const float* tc0_b  = (const float*)d_in[20];
    const float* rb_w1  = (const float*)d_in[21];
    const float* rb_b1  = (const float*)d_in[22];
    const float* rb_w2  = (const float*)d_in[23];
    const float* rb_b2  = (const float*)d_in[24];
    const float* tail_w = (const float*)d_in[25];

    float* ws = (float*)d_ws;
    float* rs    = ws;                       // 1089
    float* imgs  = rs + HWD;                 // 128*1089
    float* feats = imgs + NF * HWD;          // 128*32*1089
    float* a1c   = feats + (size_t)NF * CC * HWD;  // 124*16*1089
    float* a2    = a1c + (size_t)NJ * 16 * HWD;    // 124*16*1089
    float* agg   = a2 + (size_t)NJ * 16 * HWD;     // 124*2*1089
    float* fused = agg + (size_t)NJ * 2 * HWD;     // 124*32*1089  (also al2)
    float* offb  = fused + (size_t)NJ * CC * HWD;  // 124*18*1089  (off1 then off2)
    float* al1   = offb + (size_t)NJ * 18 * HWD;   // 124*32*1089
    float* hbuf  = feats;                    // reuse after branches (>= NJ*32*1089)
    float* tmp   = a1c;                      // reuse a1c+a2 (contiguous 32ch)
    float* al2   = fused;

    float* outF = (float*)d_out;             // final [0,135036)
    float* outA = outF + 135036 + 124;       // aligned base

    const int GF = (NF * HWD + 255) / 256;
    const int GJ = (NJ * HWD + 255) / 256;

    rowsum_k<<<HWD, 256, 0, stream>>>(mlp_w, rs);
    imgs_k<<<GF, 256, 0, stream>>>(x, rs, mlp_b, imgs);
    conv3x3_k<1, 32, true, true, false><<<GF, 256, 0, stream>>>(
        imgs, HWD, fe_w, fe_b, nullptr, 0, feats, CC * HWD, NF);
    a1c_k<<<GJ, 256, 0, stream>>>(feats, c0_w, c0_b, a1c);

    const int ioffs[4] = {-2, -1, 1, 2};
    const int cidx[4]  = {0, 1, 3, 4};
    for (int bi = 0; bi < 4; ++bi) {
        int xoff = 2 + ioffs[bi];
        a2agg_k<<<GJ, 256, 0, stream>>>(feats, c1_w, c1_b, a1c, a2, agg, xoff);
        sigfused_k<<<GJ, 256, 0, stream>>>(agg, sq_w, sq_b, a1c, a2, fused);
        conv3x3_k<32, 18, false, true, false><<<GJ, 256, 0, stream>>>(
            fused, CC * HWD, off1_w, off1_b, nullptr, 0, offb, 18 * HWD, NJ);
        deform_k<<<GJ, 256, 0, stream>>>(feats, xoff, offb, dw1, al1);
        conv3x3_k<32, 18, false, true, false><<<GJ, 256, 0, stream>>>(
            al1, CC * HWD, off2_w, off2_b, nullptr, 0, offb, 18 * HWD, NJ);
        deform_k<<<GJ, 256, 0, stream>>>(al1, 0, offb, dw2, al2);
        conv3x3_k<32, 1, false, true, false><<<GJ, 256, 0, stream>>>(
            al2, CC * HWD, conv_w, conv_b, nullptr, 0, outA + cidx[bi] * HWD, 5 * HWD, NJ);
    }

    misc_k<<<GJ, 256, 0, stream>>>(imgs, outF);

    conv3x3_k<5, 32, true, true, false><<<GJ, 256, 0, stream>>>(
        outA, 5 * HWD, tc0_w, tc0_b, nullptr, 0, hbuf, CC * HWD, NJ);
    for (int l = 0; l < 5; ++l) {
        conv3x3_k<32, 32, true, true, false><<<GJ, 256, 0, stream>>>(
            hbuf, CC * HWD, rb_w1 + (size_t)l * CC * CC * 9, rb_b1 + l * CC,
            nullptr, 0, tmp, CC * HWD, NJ);
        conv3x3_k<32, 32, false, true, true><<<GJ, 256, 0, stream>>>(
            tmp, CC * HWD, rb_w2 + (size_t)l * CC * CC * 9, rb_b2 + l * CC,
            hbuf, CC * HWD, hbuf, CC * HWD, NJ);
    }
    conv3x3_k<32, 1, false, false, false><<<GJ, 256, 0, stream>>>(
        hbuf, CC * HWD, tail_w, nullptr, nullptr, 0, outF, HWD, NJ);
}

// Round 2
// 2428.771 us; speedup vs baseline: 3.6308x; 3.6308x over previous
//
#include <hip/hip_runtime.h>
#include <math.h>

#define HWD 1089
#define WD 33
#define NF 128
#define NJ 124
#define CC 32

__device__ __forceinline__ float sigm(float z) { return 1.f / (1.f + expf(-z)); }

// ---------------- rs[j] = sum_k mlp_w[j][k] ----------------
__global__ void rowsum_k(const float* __restrict__ mw, float* __restrict__ rs) {
    int j = blockIdx.x;
    const float* row = mw + (size_t)j * HWD;
    float s = 0.f;
    for (int k = threadIdx.x; k < HWD; k += 256) s += row[k];
    __shared__ float red[256];
    red[threadIdx.x] = s; __syncthreads();
    for (int off = 128; off > 0; off >>= 1) {
        if (threadIdx.x < off) red[threadIdx.x] += red[threadIdx.x + off];
        __syncthreads();
    }
    if (threadIdx.x == 0) rs[j] = red[0];
}

// ---------------- imgs = x * sigmoid((t/20)*rs + mlp_b) ----------------
__global__ void imgs_k(const float* __restrict__ x, const float* __restrict__ rs,
                       const float* __restrict__ mb, float* __restrict__ imgs) {
    int idx = blockIdx.x * 256 + threadIdx.x;
    if (idx >= NF * HWD) return;
    int t = idx / HWD, p = idx % HWD;
    float pe = sigm(((float)t / 20.0f) * rs[p] + mb[p]);
    imgs[idx] = x[idx] * pe;
}

// ---------------- generic 3x3 conv, pad=1; LDS weights as [c][k][o] ----------------
template <int CIN, int COUT, bool RELU, bool HAS_B, bool HAS_RES>
__global__ __launch_bounds__(256, 2)
void conv3x3_k(const float* __restrict__ in, int in_ns,
               const float* __restrict__ w, const float* __restrict__ b,
               const float* __restrict__ res, int res_ns,
               float* __restrict__ out, int out_ns, int N) {
    __shared__ float wl[CIN * 9 * COUT];
    for (int i = threadIdx.x; i < COUT * CIN * 9; i += blockDim.x) {
        int o = i % COUT, r = i / COUT;
        int k = r % 9, c = r / 9;
        wl[i] = w[(o * CIN + c) * 9 + k];
    }
    __syncthreads();
    int idx = blockIdx.x * blockDim.x + threadIdx.x;
    if (idx >= N * HWD) return;
    int n = idx / HWD, p = idx % HWD;
    int h = p / WD, q = p % WD;
    float acc[COUT];
#pragma unroll
    for (int o = 0; o < COUT; ++o) acc[o] = HAS_B ? b[o] : 0.f;
    const float* inn = in + (size_t)n * in_ns;
    for (int c = 0; c < CIN; ++c) {
        float v[9];
#pragma unroll
        for (int k = 0; k < 9; ++k) {
            int hh = h + k / 3 - 1, qq = q + k % 3 - 1;
            v[k] = (hh >= 0 && hh < WD && qq >= 0 && qq < WD) ? inn[c * HWD + hh * WD + qq] : 0.f;
        }
#pragma unroll
        for (int k = 0; k < 9; ++k) {
            const float* wp = &wl[(c * 9 + k) * COUT];
#pragma unroll
            for (int o = 0; o < COUT; ++o) acc[o] += v[k] * wp[o];
        }
    }
#pragma unroll
    for (int o = 0; o < COUT; ++o) {
        float val = acc[o];
        if (RELU) val = fmaxf(val, 0.f);
        if (HAS_RES) val += res[(size_t)n * res_ns + o * HWD + p];
        out[(size_t)n * out_ns + o * HWD + p] = val;
    }
}

// ---------------- a1c = 1x1 conv (16 out) of feats[n+2] ----------------
__global__ void a1c_k(const float* __restrict__ feats, const float* __restrict__ w,
                      const float* __restrict__ b, float* __restrict__ a1c) {
    int idx = blockIdx.x * 256 + threadIdx.x;
    if (idx >= NJ * HWD) return;
    int n = idx / HWD, p = idx % HWD;
    const float* f = feats + (size_t)(n + 2) * CC * HWD + p;
    float fv[CC];
#pragma unroll
    for (int c = 0; c < CC; ++c) fv[c] = f[c * HWD];
#pragma unroll
    for (int o = 0; o < 16; ++o) {
        float acc = b[o];
#pragma unroll
        for (int c = 0; c < CC; ++c) acc += w[o * CC + c] * fv[c];
        a1c[((size_t)n * 16 + o) * HWD + p] = acc;
    }
}

// ---------------- a2 = 1x1 conv of neig; agg = [mean, max] over concat(a1c,a2) ----------------
__global__ void a2agg_k(const float* __restrict__ feats, const float* __restrict__ w,
                        const float* __restrict__ b, const float* __restrict__ a1c,
                        float* __restrict__ a2, float* __restrict__ agg, int xoff) {
    int idx = blockIdx.x * 256 + threadIdx.x;
    if (idx >= NJ * HWD) return;
    int n = idx / HWD, p = idx % HWD;
    const float* f = feats + (size_t)(n + xoff) * CC * HWD + p;
    float fv[CC];
#pragma unroll
    for (int c = 0; c < CC; ++c) fv[c] = f[c * HWD];
    float sum = 0.f, mx = -1e30f;
#pragma unroll
    for (int o = 0; o < 16; ++o) {
        float v = a1c[((size_t)n * 16 + o) * HWD + p];
        sum += v; mx = fmaxf(mx, v);
    }
#pragma unroll
    for (int o = 0; o < 16; ++o) {
        float acc = b[o];
#pragma unroll
        for (int c = 0; c < CC; ++c) acc += w[o * CC + c] * fv[c];
        a2[((size_t)n * 16 + o) * HWD + p] = acc;
        sum += acc; mx = fmaxf(mx, acc);
    }
    agg[((size_t)n * 2 + 0) * HWD + p] = sum * (1.f / 32.f);
    agg[((size_t)n * 2 + 1) * HWD + p] = mx;
}

// ---------------- sig = sigmoid(conv3x3(agg, sq_w, sq_b)); fused = [a1c*sig0, a2*sig1] ----------------
__global__ void sigfused_k(const float* __restrict__ agg, const float* __restrict__ sqw,
                           const float* __restrict__ sqb, const float* __restrict__ a1c,
                           const float* __restrict__ a2, float* __restrict__ fused) {
    int idx = blockIdx.x * 256 + threadIdx.x;
    if (idx >= NJ * HWD) return;
    int n = idx / HWD, p = idx % HWD;
    int h = p / WD, q = p % WD;
    float s0 = sqb[0], s1 = sqb[1];
    const float* ag = agg + (size_t)n * 2 * HWD;
#pragma unroll
    for (int c = 0; c < 2; ++c) {
#pragma unroll
        for (int k = 0; k < 9; ++k) {
            int hh = h + k / 3 - 1, qq = q + k % 3 - 1;
            if (hh >= 0 && hh < WD && qq >= 0 && qq < WD) {
                float v = ag[c * HWD + hh * WD + qq];
                s0 += v * sqw[(0 * 2 + c) * 9 + k];
                s1 += v * sqw[(1 * 2 + c) * 9 + k];
            }
        }
    }
    float g0 = sigm(s0), g1 = sigm(s1);
#pragma unroll
    for (int o = 0; o < 16; ++o)
        fused[((size_t)n * CC + o) * HWD + p] = a1c[((size_t)n * 16 + o) * HWD + p] * g0;
#pragma unroll
    for (int o = 0; o < 16; ++o)
        fused[((size_t)n * CC + 16 + o) * HWD + p] = a2[((size_t)n * 16 + o) * HWD + p] * g1;
}

// ---------------- deformable conv 3x3, 32->32; LDS weights as [kk][c][o] ----------------
__global__ __launch_bounds__(256, 2)
void deform_k(const float* __restrict__ xbase, int xoff,
              const float* __restrict__ off, const float* __restrict__ w,
              float* __restrict__ out) {
    __shared__ float wl[9 * CC * CC];
    for (int i = threadIdx.x; i < 9 * CC * CC; i += blockDim.x) {
        int o = i & 31, c = (i >> 5) & 31, kk = i >> 10;
        wl[i] = w[(o * CC + c) * 9 + kk];
    }
    __syncthreads();
    int idx = blockIdx.x * blockDim.x + threadIdx.x;
    if (idx >= NJ * HWD) return;
    int n = idx / HWD, p = idx % HWD;
    int h = p / WD, q = p % WD;
    const float* xf = xbase + (size_t)(n + xoff) * CC * HWD;
    const float* ofn = off + (size_t)n * 18 * HWD + p;
    float acc[CC];
#pragma unroll
    for (int o = 0; o < CC; ++o) acc[o] = 0.f;
    for (int kk = 0; kk < 9; ++kk) {
        float dy = ofn[(2 * kk) * HWD];
        float dx = ofn[(2 * kk + 1) * HWD];
        float py = (float)(h - 1 + kk / 3) + dy;
        float px = (float)(q - 1 + kk % 3) + dx;
        float y0f = floorf(py), x0f = floorf(px);
        float ly = py - y0f, lx = px - x0f;
        int y0 = (int)y0f, x0 = (int)x0f;
        float w00 = (1.f - ly) * (1.f - lx), w01 = (1.f - ly) * lx;
        float w10 = ly * (1.f - lx), w11 = ly * lx;
        bool yv0 = (y0 >= 0 && y0 < WD), yv1 = (y0 + 1 >= 0 && y0 + 1 < WD);
        bool xv0 = (x0 >= 0 && x0 < WD), xv1 = (x0 + 1 >= 0 && x0 + 1 < WD);
        if (!(yv0 && xv0)) w00 = 0.f;
        if (!(yv0 && xv1)) w01 = 0.f;
        if (!(yv1 && xv0)) w10 = 0.f;
        if (!(yv1 && xv1)) w11 = 0.f;
        int yc0 = min(max(y0, 0), WD - 1), yc1 = min(max(y0 + 1, 0), WD - 1);
        int xc0 = min(max(x0, 0), WD - 1), xc1 = min(max(x0 + 1, 0), WD - 1);
        int i00 = yc0 * WD + xc0, i01 = yc0 * WD + xc1;
        int i10 = yc1 * WD + xc0, i11 = yc1 * WD + xc1;
        const float* wk = &wl[kk * CC * CC];
        for (int c = 0; c < CC; ++c) {
            const float* xc = xf + c * HWD;
            float s = xc[i00] * w00 + xc[i01] * w01 + xc[i10] * w10 + xc[i11] * w11;
            const float* wp = wk + c * CC;
#pragma unroll
            for (int o = 0; o < CC; ++o) acc[o] += s * wp[o];
        }
    }
#pragma unroll
    for (int o = 0; o < CC; ++o) out[((size_t)n * CC + o) * HWD + p] = acc[o];
}

// ---------------- cen_raw into aligned ch2 + arange output ----------------
__global__ void misc_k(const float* __restrict__ imgs, float* __restrict__ out) {
    int idx = blockIdx.x * 256 + threadIdx.x;
    float* alig = out + 135036 + 124;
    if (idx < NJ * HWD) {
        int n = idx / HWD, p = idx % HWD;
        alig[((size_t)n * 5 + 2) * HWD + p] = imgs[(size_t)(n + 2) * HWD + p];
    }
    if (idx < NJ) out[135036 + idx] = (float)(idx + 2);
}

extern "C" void kernel_launch(void* const* d_in, const int* in_sizes, int n_in,
                              void* d_out, int out_size, void* d_ws, size_t ws_size,
                              hipStream_t stream) {
    const float* x      = (const float*)d_in[0];
    const float* mlp_w  = (const float*)d_in[1];
    const float* mlp_b  = (const float*)d_in[2];
    const float* fe_w   = (const float*)d_in[3];
    const float* fe_b   = (const float*)d_in[4];
    const float* c0_w   = (const float*)d_in[5];
    const float* c0_b   = (const float*)d_in[6];
    const float* c1_w   = (const float*)d_in[7];
    const float* c1_b   = (const float*)d_in[8];
    const float* sq_w   = (const float*)d_in[9];
    const float* sq_b   = (const float*)d_in[10];
    const float* off1_w = (const float*)d_in[11];
    const float* off1_b = (const float*)d_in[12];
    const float* dw1    = (const float*)d_in[13];
    const float* off2_w = (const float*)d_in[14];
    const float* off2_b = (const float*)d_in[15];
    const float* dw2    = (const float*)d_in[16];
    const float* conv_w = (const float*)d_in[17];
    const float* conv_b = (const float*)d_in[18];
    const float* tc0_w  = (const float*)d_in[19];
    const float* tc0_b  = (const float*)d_in[20];
    const float* rb_w1  = (const float*)d_in[21];
    const float* rb_b1  = (const float*)d_in[22];
    const float* rb_w2  = (const float*)d_in[23];
    const float* rb_b2  = (const float*)d_in[24];
    const float* tail_w = (const float*)d_in[25];

    float* ws = (float*)d_ws;
    float* rs    = ws;                       // 1089
    float* imgs  = rs + HWD;                 // 128*1089
    float* feats = imgs + NF * HWD;          // 128*32*1089
    float* a1c   = feats + (size_t)NF * CC * HWD;  // 124*16*1089
    float* a2    = a1c + (size_t)NJ * 16 * HWD;    // 124*16*1089
    float* agg   = a2 + (size_t)NJ * 16 * HWD;     // 124*2*1089
    float* fused = agg + (size_t)NJ * 2 * HWD;     // 124*32*1089  (also al2)
    float* offb  = fused + (size_t)NJ * CC * HWD;  // 124*18*1089  (off1 then off2)
    float* al1   = offb + (size_t)NJ * 18 * HWD;   // 124*32*1089
    float* hbuf  = feats;                    // reuse after branches (>= NJ*32*1089)
    float* tmp   = a1c;                      // reuse a1c+a2 (contiguous 32ch)
    float* al2   = fused;

    float* outF = (float*)d_out;             // final [0,135036)
    float* outA = outF + 135036 + 124;       // aligned base

    const int GF = (NF * HWD + 255) / 256;
    const int GJ = (NJ * HWD + 255) / 256;

    rowsum_k<<<HWD, 256, 0, stream>>>(mlp_w, rs);
    imgs_k<<<GF, 256, 0, stream>>>(x, rs, mlp_b, imgs);
    conv3x3_k<1, 32, true, true, false><<<GF, 256, 0, stream>>>(
        imgs, HWD, fe_w, fe_b, nullptr, 0, feats, CC * HWD, NF);
    a1c_k<<<GJ, 256, 0, stream>>>(feats, c0_w, c0_b, a1c);

    const int ioffs[4] = {-2, -1, 1, 2};
    const int cidx[4]  = {0, 1, 3, 4};
    for (int bi = 0; bi < 4; ++bi) {
        int xoff = 2 + ioffs[bi];
        a2agg_k<<<GJ, 256, 0, stream>>>(feats, c1_w, c1_b, a1c, a2, agg, xoff);
        sigfused_k<<<GJ, 256, 0, stream>>>(agg, sq_w, sq_b, a1c, a2, fused);
        conv3x3_k<32, 18, false, true, false><<<GJ, 256, 0, stream>>>(
            fused, CC * HWD, off1_w, off1_b, nullptr, 0, offb, 18 * HWD, NJ);
        deform_k<<<GJ, 256, 0, stream>>>(feats, xoff, offb, dw1, al1);
        conv3x3_k<32, 18, false, true, false><<<GJ, 256, 0, stream>>>(
            al1, CC * HWD, off2_w, off2_b, nullptr, 0, offb, 18 * HWD, NJ);
        deform_k<<<GJ, 256, 0, stream>>>(al1, 0, offb, dw2, al2);
        conv3x3_k<32, 1, false, true, false><<<GJ, 256, 0, stream>>>(
            al2, CC * HWD, conv_w, conv_b, nullptr, 0, outA + cidx[bi] * HWD, 5 * HWD, NJ);
    }

    misc_k<<<GJ, 256, 0, stream>>>(imgs, outF);

    conv3x3_k<5, 32, true, true, false><<<GJ, 256, 0, stream>>>(
        outA, 5 * HWD, tc0_w, tc0_b, nullptr, 0, hbuf, CC * HWD, NJ);
    for (int l = 0; l < 5; ++l) {
        conv3x3_k<32, 32, true, true, false><<<GJ, 256, 0, stream>>>(
            hbuf, CC * HWD, rb_w1 + (size_t)l * CC * CC * 9, rb_b1 + l * CC,
            nullptr, 0, tmp, CC * HWD, NJ);
        conv3x3_k<32, 32, false, true, true><<<GJ, 256, 0, stream>>>(
            tmp, CC * HWD, rb_w2 + (size_t)l * CC * CC * 9, rb_b2 + l * CC,
            hbuf, CC * HWD, hbuf, CC * HWD, NJ);
    }
    conv3x3_k<32, 1, false, false, false><<<GJ, 256, 0, stream>>>(
        hbuf, CC * HWD, tail_w, nullptr, nullptr, 0, outF, HWD, NJ);
}